// Round 12
// baseline (60.333 us; speedup 1.0000x reference)
//
#include <hip/hip_runtime.h>
#include <math.h>

#define NOBJ  32
#define NANCH 16384
#define NTOT  131072      // 8 * 16384
#define MBLK  256         // dl_main blocks (512 threads, 1 anchor/thread)
#define NREP  8           // global histogram replicas (+ arrival groups)
#define NBUK  2048        // clamped exponent+4-mantissa-bit buckets
#define BOFF  1792        // bucket offset: (bits>>19) - BOFF, clamped to [0,NBUK)

// ---- ws word layout ----
#define OFF_SLOTS 64                 // 256 blocks * 8 words (np, nn, box, pos, wsum)
#define OFF_ARR   2112               // 8 group counters (stride 16) + root at +128; pad 256
#define OFF_HC    2368               // NREP * (cnt[NBUK] + f32 sum[NBUK]) = 32768 words
#define ZERO_U4   8256               // (256 + 32768) / 4 uint4s to clear
// total = OFF_HC + 32768 = 35136 words ~= 141 KB (ws proven far larger)

__device__ __forceinline__ float smooth_l1f(float d) {
    float ad = fabsf(d);
    return ad < 1.0f ? 0.5f * ad * ad : ad - 0.5f;
}

__device__ __forceinline__ unsigned ld_au(const unsigned* p) {
    return __hip_atomic_load(p, __ATOMIC_RELAXED, __HIP_MEMORY_SCOPE_AGENT);
}
__device__ __forceinline__ float ld_af(const float* p) {
    return __hip_atomic_load(p, __ATOMIC_RELAXED, __HIP_MEMORY_SCOPE_AGENT);
}

// kernel 1: zero arrival counters + histogram replicas
__global__ __launch_bounds__(256) void dl_zero(unsigned int* __restrict__ ws)
{
    int i = blockIdx.x * 256 + threadIdx.x;
    if (i < ZERO_U4)
        reinterpret_cast<uint4*>(ws + OFF_ARR)[i] = make_uint4(0u, 0u, 0u, 0u);
}

// kernel 2: per-anchor compute + LDS hist + replica merge + last-block tail
__global__ __launch_bounds__(512) void dl_main(
    const float* __restrict__ pred_boxes,
    const float* __restrict__ pred_classes,
    const float* __restrict__ true_boxes,
    const int*   __restrict__ true_classes,
    const float* __restrict__ anchors,
    unsigned int* __restrict__ ws,
    float* __restrict__ out)
{
    __shared__ float    s_tb[NOBJ * 4];
    __shared__ int      s_tc[NOBJ];
    __shared__ unsigned lcnt[2][NBUK];
    __shared__ float    lsum[2][NBUK];
    __shared__ int      s_wi[8][2];
    __shared__ float    s_wf[8][3];
    __shared__ int      wti[8];
    __shared__ float    wtf[8];
    __shared__ int      s_fin;
    __shared__ int      sh_k;
    __shared__ float    sh_fp, sh_fw, sh_box, sh_denom;

    const int t = threadIdx.x;
    const int idx = blockIdx.x * 512 + t;   // 32 blocks per image; no straddling
    const int b = idx >> 14;
    const int a = idx & (NANCH - 1);
    if (t < NOBJ * 4) s_tb[t] = true_boxes[b * NOBJ * 4 + t];
    if (t < NOBJ)     s_tc[t] = true_classes[b * NOBJ + t];
    for (int i = t; i < 2 * NBUK; i += 512) { (&lcnt[0][0])[i] = 0u; (&lsum[0][0])[i] = 0.f; }
    __syncthreads();

    float4 anc = reinterpret_cast<const float4*>(anchors)[a];   // (cx, cy, w, h)
    float ax1 = anc.x - anc.z * 0.5f;
    float ay1 = anc.y - anc.w * 0.5f;
    float ax2 = anc.x + anc.z * 0.5f;
    float ay2 = anc.y + anc.w * 0.5f;
    float area_a = (ax2 - ax1) * (ay2 - ay1);

    float ov[NOBJ];
    float best = -3.402823466e38f;
#pragma unroll
    for (int o = 0; o < NOBJ; ++o) {
        float v;
        if (s_tc[o] < 0) {
            v = -1.0f;   // reference masks padded slots' overlap to -1
        } else {
            float bx1 = s_tb[o * 4 + 0], by1 = s_tb[o * 4 + 1];
            float bx2 = s_tb[o * 4 + 2], by2 = s_tb[o * 4 + 3];
            float ltx = fmaxf(ax1, bx1), lty = fmaxf(ay1, by1);
            float rbx = fminf(ax2, bx2), rby = fminf(ay2, by2);
            float w = fmaxf(rbx - ltx, 0.0f), h = fmaxf(rby - lty, 0.0f);
            float inter = w * h;
            float area_b = (bx2 - bx1) * (by2 - by1);
            v = inter / (area_a + area_b - inter);
        }
        ov[o] = v;
        best = fmaxf(best, v);
    }

    // log-softmax over 2 classes
    float2 pc = reinterpret_cast<const float2*>(pred_classes)[idx];
    float mx = fmaxf(pc.x, pc.y);
    float lse = mx + logf(expf(pc.x - mx) + expf(pc.y - mx));
    float l0 = pc.x - lse;
    float l1 = pc.y - lse;

    // negative: best < 0.5. Bucket nce by exponent + top-4 mantissa bits
    const int wave = t >> 6, lane = t & 63, rep = wave & 1;
    int isneg = 0;
    if (best < 0.5f) {
        float nce = -l0;
        int bk = (int)(__float_as_uint(nce) >> 19) - BOFF;
        bk = bk < 0 ? 0 : (bk > NBUK - 1 ? NBUK - 1 : bk);
        atomicAdd(&lcnt[rep][bk], 1u);
        atomicAdd(&lsum[rep][bk], nce);
        isneg = 1;
    }

    // positives: per o, |best - ov| < 1e-6 and ov > 0.5
    float4 pb = reinterpret_cast<const float4*>(pred_boxes)[idx];
    int npos = 0; float boxs = 0.f, poss = 0.f, wsum = 0.f;
#pragma unroll
    for (int o = 0; o < NOBJ; ++o) {
        float v = ov[o];
        if (fabsf(best - v) < 1e-6f && v > 0.5f) {
            ++npos;
            float bx1 = s_tb[o * 4 + 0], by1 = s_tb[o * 4 + 1];
            float bx2 = s_tb[o * 4 + 2], by2 = s_tb[o * 4 + 3];
            float gcx = ((bx1 + bx2) * 0.5f - anc.x) / (0.1f * anc.z);
            float gcy = ((by1 + by2) * 0.5f - anc.y) / (0.1f * anc.w);
            float gw  = logf((bx2 - bx1) / anc.z) / 0.2f;
            float gh  = logf((by2 - by1) / anc.w) / 0.2f;
            boxs += smooth_l1f(pb.x - gcx) + smooth_l1f(pb.y - gcy)
                  + smooth_l1f(pb.z - gw)  + smooth_l1f(pb.w - gh);
            int c = s_tc[o];
            float w = (c == 1) ? 4.0f : 1.0f;
            poss += w * ((c == 1) ? -l1 : -l0);
            wsum += w;
        }
    }

    // block reduce the 5 stats (8 waves)
    int ip = npos, ng = isneg;
    float fb = boxs, fp = poss, fw = wsum;
#pragma unroll
    for (int o = 32; o; o >>= 1) {
        ip += __shfl_down(ip, o); ng += __shfl_down(ng, o);
        fb += __shfl_down(fb, o); fp += __shfl_down(fp, o); fw += __shfl_down(fw, o);
    }
    if (lane == 0) {
        s_wi[wave][0] = ip; s_wi[wave][1] = ng;
        s_wf[wave][0] = fb; s_wf[wave][1] = fp; s_wf[wave][2] = fw;
    }
    __syncthreads();   // covers LDS hist atomics + s_w* stores
    if (t == 0) {
        int tp = 0, tn = 0; float t2 = 0.f, t3 = 0.f, t4 = 0.f;
        for (int w = 0; w < 8; ++w) {
            tp += s_wi[w][0]; tn += s_wi[w][1];
            t2 += s_wf[w][0]; t3 += s_wf[w][1]; t4 += s_wf[w][2];
        }
        unsigned* sl = ws + OFF_SLOTS + blockIdx.x * 8;
        sl[0] = (unsigned)tp; sl[1] = (unsigned)tn;
        sl[2] = __float_as_uint(t2); sl[3] = __float_as_uint(t3); sl[4] = __float_as_uint(t4);
    }
    // merge nonzero buckets into this block's replica (chains <= MBLK/NREP = 32)
    unsigned* gc = ws + OFF_HC + (blockIdx.x & (NREP - 1)) * (NBUK * 2);
    float*    gs = reinterpret_cast<float*>(gc + NBUK);
    for (int i = t; i < NBUK; i += 512) {
        unsigned c = lcnt[0][i] + lcnt[1][i];
        if (c) { atomicAdd(gc + i, c); atomicAdd(gs + i, lsum[0][i] + lsum[1][i]); }
    }

    // ---- tree arrival: globally-last block runs the tail inline ----
    __threadfence();
    __syncthreads();
    if (t == 0) {
        s_fin = 0;
        int grp = blockIdx.x & (NREP - 1);
        unsigned ga = __hip_atomic_fetch_add(ws + OFF_ARR + grp * 16, 1u,
                                             __ATOMIC_ACQ_REL, __HIP_MEMORY_SCOPE_AGENT) + 1u;
        if (ga == MBLK / NREP) {
            unsigned ra = __hip_atomic_fetch_add(ws + OFF_ARR + 128, 1u,
                                                 __ATOMIC_ACQ_REL, __HIP_MEMORY_SCOPE_AGENT) + 1u;
            if (ra == NREP) s_fin = 1;
        }
    }
    __syncthreads();
    if (!s_fin) return;

    // ===== TAIL (one block, 512 threads): slots reduce + cutoff + outputs =====
    {
        int np = 0, nn = 0; float fb2 = 0.f, fp2 = 0.f, fw2 = 0.f;
        if (t < MBLK) {
            const unsigned* sl = ws + OFF_SLOTS + t * 8;
            np = (int)ld_au(sl + 0); nn = (int)ld_au(sl + 1);
            fb2 = ld_af((const float*)sl + 2);
            fp2 = ld_af((const float*)sl + 3);
            fw2 = ld_af((const float*)sl + 4);
        }
#pragma unroll
        for (int o = 32; o; o >>= 1) {
            np += __shfl_down(np, o); nn += __shfl_down(nn, o);
            fb2 += __shfl_down(fb2, o); fp2 += __shfl_down(fp2, o); fw2 += __shfl_down(fw2, o);
        }
        if (lane == 0 && wave < 4) {
            s_wi[wave][0] = np; s_wi[wave][1] = nn;
            s_wf[wave][0] = fb2; s_wf[wave][1] = fp2; s_wf[wave][2] = fw2;
        }
        __syncthreads();
        if (t == 0) {
            int tp = 0, tn = 0; float t2 = 0.f, t3 = 0.f, t4 = 0.f;
            for (int w = 0; w < 4; ++w) {
                tp += s_wi[w][0]; tn += s_wi[w][1];
                t2 += s_wf[w][0]; t3 += s_wf[w][1]; t4 += s_wf[w][2];
            }
            long long k10 = 10LL * (long long)tp;
            int k = (int)((k10 < (long long)tn) ? k10 : (long long)tn);
            sh_k = k;
            sh_fp = t3; sh_fw = t4;
            sh_denom = (float)(tp > 1 ? tp : 1);
            sh_box = t2 / sh_denom;
        }
        __syncthreads();
        const int k = sh_k;
        if (k == 0) {
            if (t == 0) {
                float cls = 10.0f * sh_fp / fmaxf(sh_fw, 1e-6f) / sh_denom;
                out[0] = sh_box; out[1] = cls; out[2] = sh_box + cls;
            }
            return;
        }

        // merge NREP replicas: thread t owns buckets [4t, 4t+4)
        unsigned cbk[4] = {0u, 0u, 0u, 0u};
        float    sbk[4] = {0.f, 0.f, 0.f, 0.f};
#pragma unroll
        for (int r = 0; r < NREP; ++r) {
            const unsigned* gcr = ws + OFF_HC + r * (NBUK * 2);
            const float*    gsr = (const float*)(gcr + NBUK);
#pragma unroll
            for (int i = 0; i < 4; ++i) {
                cbk[i] += ld_au(gcr + t * 4 + i);
                sbk[i] += ld_af(gsr + t * 4 + i);
            }
        }
        int   cc = (int)(cbk[0] + cbk[1] + cbk[2] + cbk[3]);
        float ss = sbk[0] + sbk[1] + sbk[2] + sbk[3];

        // suffix-inclusive scan (count + float sum): wave shuffles + 8 wave totals
        int v = cc; float f = ss;
#pragma unroll
        for (int o = 1; o < 64; o <<= 1) {
            int   u2 = __shfl_down(v, o);
            float g2 = __shfl_down(f, o);
            if (lane + o < 64) { v += u2; f += g2; }
        }
        if (lane == 0) { wti[wave] = v; wtf[wave] = f; }
        __syncthreads();
        int S = v; float FS = f;
        for (int w = wave + 1; w < 8; ++w) { S += wti[w]; FS += wtf[w]; }

        if (S >= k && S - cc < k) {   // exactly one winner thread
            int   cum  = S - cc;
            float facc = FS - ss;
            float sfx = 0.f;
            for (int bq = 3; bq >= 0; --bq) {
                int cb = (int)cbk[bq];
                if (cum + cb >= k) {
                    int r1 = k - cum;   // take r1 of cb from the cut bucket (mean approx)
                    float sneg = facc + sfx + (float)r1 * (sbk[bq] / (float)cb);
                    float cls = 10.0f * (sh_fp + sneg)
                              / fmaxf(sh_fw + (float)k, 1e-6f) / sh_denom;
                    out[0] = sh_box; out[1] = cls; out[2] = sh_box + cls;
                    break;
                }
                cum += cb; sfx += sbk[bq];
            }
        }
    }
}

extern "C" void kernel_launch(void* const* d_in, const int* in_sizes, int n_in,
                              void* d_out, int out_size, void* d_ws, size_t ws_size,
                              hipStream_t stream)
{
    const float* pred_boxes   = (const float*)d_in[0];
    const float* pred_classes = (const float*)d_in[1];
    const float* true_boxes   = (const float*)d_in[2];
    const int*   true_classes = (const int*)d_in[3];
    const float* anchors      = (const float*)d_in[4];
    unsigned int* ws = (unsigned int*)d_ws;

    dl_zero<<<33, 256, 0, stream>>>(ws);
    dl_main<<<MBLK, 512, 0, stream>>>(pred_boxes, pred_classes, true_boxes,
                                      true_classes, anchors, ws, (float*)d_out);
}

// Round 13
// 26.280 us; speedup vs baseline: 2.2958x; 2.2958x over previous
//
#include <hip/hip_runtime.h>
#include <math.h>

#define NOBJ  32
#define NANCH 16384
#define NTOT  131072      // 8 * 16384
#define MBLK  256         // dl_main blocks (512 threads, 1 anchor/thread)
#define NREP  8           // global histogram replicas
#define NBUK  2048        // clamped exponent+4-mantissa-bit buckets
#define BOFF  1792        // bucket offset: (bits>>19) - BOFF, clamped to [0,NBUK)

// ---- ws word layout ----
#define OFF_SLOTS 64                 // 256 blocks * 8 words (np, nn, box, pos, wsum)
#define OFF_HC    2112               // NREP * (cnt[NBUK] + f32 sum[NBUK]) = 32768 words
#define HWORDS    (NREP * NBUK * 2)
// total = OFF_HC + HWORDS = 34880 words ~= 140 KB (ws proven far larger)

__device__ __forceinline__ float smooth_l1f(float d) {
    float ad = fabsf(d);
    return ad < 1.0f ? 0.5f * ad * ad : ad - 0.5f;
}

// kernel 1: zero the histogram replicas (32 blocks * 256 threads * uint4 = 32768 words)
__global__ __launch_bounds__(256) void dl_zero(unsigned int* __restrict__ ws)
{
    int i = blockIdx.x * 256 + threadIdx.x;
    reinterpret_cast<uint4*>(ws + OFF_HC)[i] = make_uint4(0u, 0u, 0u, 0u);
}

// kernel 2: per-anchor compute (proven math) + x2-replicated LDS hist + replica merge
__global__ __launch_bounds__(512) void dl_main(
    const float* __restrict__ pred_boxes,
    const float* __restrict__ pred_classes,
    const float* __restrict__ true_boxes,
    const int*   __restrict__ true_classes,
    const float* __restrict__ anchors,
    unsigned int* __restrict__ ws)
{
    __shared__ float    s_tb[NOBJ * 4];
    __shared__ int      s_tc[NOBJ];
    __shared__ unsigned lcnt[2][NBUK];
    __shared__ float    lsum[2][NBUK];
    __shared__ int      s_wi[8][2];
    __shared__ float    s_wf[8][3];

    const int t = threadIdx.x;
    const int idx = blockIdx.x * 512 + t;   // 32 blocks per image; no straddling
    const int b = idx >> 14;
    const int a = idx & (NANCH - 1);
    if (t < NOBJ * 4) s_tb[t] = true_boxes[b * NOBJ * 4 + t];
    if (t < NOBJ)     s_tc[t] = true_classes[b * NOBJ + t];
    for (int i = t; i < 2 * NBUK; i += 512) { (&lcnt[0][0])[i] = 0u; (&lsum[0][0])[i] = 0.f; }
    __syncthreads();

    float4 anc = reinterpret_cast<const float4*>(anchors)[a];   // (cx, cy, w, h)
    float ax1 = anc.x - anc.z * 0.5f;
    float ay1 = anc.y - anc.w * 0.5f;
    float ax2 = anc.x + anc.z * 0.5f;
    float ay2 = anc.y + anc.w * 0.5f;
    float area_a = (ax2 - ax1) * (ay2 - ay1);

    float ov[NOBJ];
    float best = -3.402823466e38f;
#pragma unroll
    for (int o = 0; o < NOBJ; ++o) {
        float v;
        if (s_tc[o] < 0) {
            v = -1.0f;   // reference masks padded slots' overlap to -1
        } else {
            float bx1 = s_tb[o * 4 + 0], by1 = s_tb[o * 4 + 1];
            float bx2 = s_tb[o * 4 + 2], by2 = s_tb[o * 4 + 3];
            float ltx = fmaxf(ax1, bx1), lty = fmaxf(ay1, by1);
            float rbx = fminf(ax2, bx2), rby = fminf(ay2, by2);
            float w = fmaxf(rbx - ltx, 0.0f), h = fmaxf(rby - lty, 0.0f);
            float inter = w * h;
            float area_b = (bx2 - bx1) * (by2 - by1);
            v = inter / (area_a + area_b - inter);
        }
        ov[o] = v;
        best = fmaxf(best, v);
    }

    // log-softmax over 2 classes
    float2 pc = reinterpret_cast<const float2*>(pred_classes)[idx];
    float mx = fmaxf(pc.x, pc.y);
    float lse = mx + logf(expf(pc.x - mx) + expf(pc.y - mx));
    float l0 = pc.x - lse;
    float l1 = pc.y - lse;

    // negative: best < 0.5. Bucket nce by exponent + top-4 mantissa bits,
    // offset by BOFF and clamped -> NBUK monotone buckets.
    const int wave = t >> 6, lane = t & 63, rep = wave & 1;
    int isneg = 0;
    if (best < 0.5f) {
        float nce = -l0;
        int bk = (int)(__float_as_uint(nce) >> 19) - BOFF;
        bk = bk < 0 ? 0 : (bk > NBUK - 1 ? NBUK - 1 : bk);
        atomicAdd(&lcnt[rep][bk], 1u);
        atomicAdd(&lsum[rep][bk], nce);
        isneg = 1;
    }

    // positives: per o, |best - ov| < 1e-6 and ov > 0.5
    float4 pb = reinterpret_cast<const float4*>(pred_boxes)[idx];
    int npos = 0; float boxs = 0.f, poss = 0.f, wsum = 0.f;
#pragma unroll
    for (int o = 0; o < NOBJ; ++o) {
        float v = ov[o];
        if (fabsf(best - v) < 1e-6f && v > 0.5f) {
            ++npos;
            float bx1 = s_tb[o * 4 + 0], by1 = s_tb[o * 4 + 1];
            float bx2 = s_tb[o * 4 + 2], by2 = s_tb[o * 4 + 3];
            float gcx = ((bx1 + bx2) * 0.5f - anc.x) / (0.1f * anc.z);
            float gcy = ((by1 + by2) * 0.5f - anc.y) / (0.1f * anc.w);
            float gw  = logf((bx2 - bx1) / anc.z) / 0.2f;
            float gh  = logf((by2 - by1) / anc.w) / 0.2f;
            boxs += smooth_l1f(pb.x - gcx) + smooth_l1f(pb.y - gcy)
                  + smooth_l1f(pb.z - gw)  + smooth_l1f(pb.w - gh);
            int c = s_tc[o];
            float w = (c == 1) ? 4.0f : 1.0f;
            poss += w * ((c == 1) ? -l1 : -l0);
            wsum += w;
        }
    }

    // block reduce the 5 stats (8 waves)
    int ip = npos, ng = isneg;
    float fb = boxs, fp = poss, fw = wsum;
#pragma unroll
    for (int o = 32; o; o >>= 1) {
        ip += __shfl_down(ip, o); ng += __shfl_down(ng, o);
        fb += __shfl_down(fb, o); fp += __shfl_down(fp, o); fw += __shfl_down(fw, o);
    }
    if (lane == 0) {
        s_wi[wave][0] = ip; s_wi[wave][1] = ng;
        s_wf[wave][0] = fb; s_wf[wave][1] = fp; s_wf[wave][2] = fw;
    }
    __syncthreads();   // covers LDS hist atomics + s_w* stores
    if (t == 0) {
        int tp = 0, tn = 0; float t2 = 0.f, t3 = 0.f, t4 = 0.f;
        for (int w = 0; w < 8; ++w) {
            tp += s_wi[w][0]; tn += s_wi[w][1];
            t2 += s_wf[w][0]; t3 += s_wf[w][1]; t4 += s_wf[w][2];
        }
        unsigned* sl = ws + OFF_SLOTS + blockIdx.x * 8;
        sl[0] = (unsigned)tp; sl[1] = (unsigned)tn;
        sl[2] = __float_as_uint(t2); sl[3] = __float_as_uint(t3); sl[4] = __float_as_uint(t4);
    }
    // merge nonzero buckets into this block's replica (chains <= MBLK/NREP = 32)
    unsigned* gc = ws + OFF_HC + (blockIdx.x & (NREP - 1)) * (NBUK * 2);
    float*    gs = reinterpret_cast<float*>(gc + NBUK);
    for (int i = t; i < NBUK; i += 512) {
        unsigned c = lcnt[0][i] + lcnt[1][i];
        if (c) { atomicAdd(gc + i, c); atomicAdd(gs + i, lsum[0][i] + lsum[1][i]); }
    }
}

// kernel 3: one block — merge replicas, suffix-scan, cutoff, outputs
__global__ __launch_bounds__(1024) void dl_tail(const unsigned int* __restrict__ ws,
                                                float* __restrict__ out)
{
    __shared__ int   s_wi[16][2];
    __shared__ float s_wf[16][3];
    __shared__ int   wti[16];
    __shared__ float wtf[16];
    __shared__ int   sh_k;
    __shared__ float sh_fp, sh_fw, sh_box, sh_denom;

    const int t = threadIdx.x, wave = t >> 6, lane = t & 63;

    // reduce dl_main slots (256 of them live in waves 0..3)
    int np = 0, nn = 0; float fb = 0.f, fp = 0.f, fw = 0.f;
    if (t < MBLK) {
        const unsigned* sl = ws + OFF_SLOTS + t * 8;
        np = (int)sl[0]; nn = (int)sl[1];
        fb = __uint_as_float(sl[2]); fp = __uint_as_float(sl[3]); fw = __uint_as_float(sl[4]);
    }
#pragma unroll
    for (int o = 32; o; o >>= 1) {
        np += __shfl_down(np, o); nn += __shfl_down(nn, o);
        fb += __shfl_down(fb, o); fp += __shfl_down(fp, o); fw += __shfl_down(fw, o);
    }
    if (lane == 0 && wave < 4) {
        s_wi[wave][0] = np; s_wi[wave][1] = nn;
        s_wf[wave][0] = fb; s_wf[wave][1] = fp; s_wf[wave][2] = fw;
    }
    __syncthreads();
    if (t == 0) {
        int tp = 0, tn = 0; float t2 = 0.f, t3 = 0.f, t4 = 0.f;
        for (int w = 0; w < 4; ++w) {
            tp += s_wi[w][0]; tn += s_wi[w][1];
            t2 += s_wf[w][0]; t3 += s_wf[w][1]; t4 += s_wf[w][2];
        }
        long long k10 = 10LL * (long long)tp;
        int k = (int)((k10 < (long long)tn) ? k10 : (long long)tn);
        sh_k = k;
        sh_fp = t3; sh_fw = t4;
        sh_denom = (float)(tp > 1 ? tp : 1);
        sh_box = t2 / sh_denom;
    }
    __syncthreads();
    const int k = sh_k;
    if (k == 0) {
        if (t == 0) {
            float cls = 10.0f * sh_fp / fmaxf(sh_fw, 1e-6f) / sh_denom;
            out[0] = sh_box; out[1] = cls; out[2] = sh_box + cls;
        }
        return;
    }

    // merge NREP replicas: thread t owns buckets [2t, 2t+2)
    unsigned cbk[2] = {0u, 0u};
    float    sbk[2] = {0.f, 0.f};
#pragma unroll
    for (int r = 0; r < NREP; ++r) {
        uint2  u = *reinterpret_cast<const uint2*>(ws + OFF_HC + r * (NBUK * 2) + t * 2);
        float2 s = *reinterpret_cast<const float2*>(ws + OFF_HC + r * (NBUK * 2) + NBUK + t * 2);
        cbk[0] += u.x; cbk[1] += u.y;
        sbk[0] += s.x; sbk[1] += s.y;
    }
    int   cc = (int)(cbk[0] + cbk[1]);
    float ss = sbk[0] + sbk[1];

    // suffix-inclusive scan (count + float sum): wave shuffles + 16 wave totals
    int v = cc; float f = ss;
#pragma unroll
    for (int o = 1; o < 64; o <<= 1) {
        int   u2 = __shfl_down(v, o);
        float g2 = __shfl_down(f, o);
        if (lane + o < 64) { v += u2; f += g2; }
    }
    if (lane == 0) { wti[wave] = v; wtf[wave] = f; }
    __syncthreads();
    int S = v; float FS = f;
    for (int w = wave + 1; w < 16; ++w) { S += wti[w]; FS += wtf[w]; }

    if (S >= k && S - cc < k) {   // exactly one winner thread
        int   cum  = S - cc;      // count in buckets strictly above this thread's 2
        float facc = FS - ss;     // float sum of those buckets (exact)
        float sfx = 0.f;
        for (int bq = 1; bq >= 0; --bq) {
            int cb = (int)cbk[bq];
            if (cum + cb >= k) {
                int r1 = k - cum;     // take r1 of cb from the cut bucket (mean approx)
                float sneg = facc + sfx + (float)r1 * (sbk[bq] / (float)cb);
                float cls = 10.0f * (sh_fp + sneg)
                          / fmaxf(sh_fw + (float)k, 1e-6f) / sh_denom;
                out[0] = sh_box; out[1] = cls; out[2] = sh_box + cls;
                break;
            }
            cum += cb; sfx += sbk[bq];
        }
    }
}

extern "C" void kernel_launch(void* const* d_in, const int* in_sizes, int n_in,
                              void* d_out, int out_size, void* d_ws, size_t ws_size,
                              hipStream_t stream)
{
    const float* pred_boxes   = (const float*)d_in[0];
    const float* pred_classes = (const float*)d_in[1];
    const float* true_boxes   = (const float*)d_in[2];
    const int*   true_classes = (const int*)d_in[3];
    const float* anchors      = (const float*)d_in[4];
    unsigned int* ws = (unsigned int*)d_ws;

    dl_zero<<<32, 256, 0, stream>>>(ws);
    dl_main<<<MBLK, 512, 0, stream>>>(pred_boxes, pred_classes, true_boxes,
                                      true_classes, anchors, ws);
    dl_tail<<<1, 1024, 0, stream>>>(ws, (float*)d_out);
}